// Round 3
// baseline (848.790 us; speedup 1.0000x reference)
//
#include <hip/hip_runtime.h>

// Scaled-dot-product attention, bs=4, h=16, S=2048, D=64, f32 in/out.
// Outputs O [64,2048,64] and P=attn_weights [64,2048,2048] (f32, 1.07 GB write).
// Swapped-QK^T 32x32 structure: S^T = mfma(K, Q^T) -> j is lane-local per q-row,
// softmax denom needs no cross-lane in loop; P->bf16 A-frags via bf16-pack +
// v_permlane32_swap (no LDS, no barriers). Memory-bound on the P write.

#define S_LEN 2048
#define DH 64
#define NHEADS 64  // bs*h

typedef short short8 __attribute__((ext_vector_type(8)));   // 8 x bf16
typedef float f32x4 __attribute__((ext_vector_type(4)));
typedef float f32x16 __attribute__((ext_vector_type(16)));
typedef unsigned short u16;

__device__ __forceinline__ u16 f2bf(float f) {
  union { float f; unsigned u; } x;
  x.f = f;
  unsigned r = x.u + 0x7fffu + ((x.u >> 16) & 1u);  // RNE
  return (u16)(r >> 16);
}

__device__ __forceinline__ unsigned pkbf(float a, float b) {
  return (unsigned)f2bf(a) | ((unsigned)f2bf(b) << 16);  // a -> low, b -> high
}

// v_permlane32_swap_b32: new a[32+i]=old b[i]; new b[i]=old a[32+i]
__device__ __forceinline__ void plswap(unsigned& a, unsigned& b) {
  asm("v_permlane32_swap_b32 %0, %1" : "+v"(a), "+v"(b));
}

// ---- pre-pass: Q * scale -> bf16, same layout ----
__global__ __launch_bounds__(256) void cvt_scale_k(const float* __restrict__ in,
                                                   u16* __restrict__ out,
                                                   float scale, int n4) {
  int i = blockIdx.x * 256 + threadIdx.x;
  if (i >= n4) return;
  float4 v = ((const float4*)in)[i];
  union { u16 s[4]; unsigned long long ll; } o;
  o.s[0] = f2bf(v.x * scale); o.s[1] = f2bf(v.y * scale);
  o.s[2] = f2bf(v.z * scale); o.s[3] = f2bf(v.w * scale);
  ((unsigned long long*)out)[i] = o.ll;
}

// ---- pre-pass: per-head transpose [R][C] f32 -> [C][R] bf16 ----
__global__ __launch_bounds__(256) void transpose_cvt_k(const float* __restrict__ in,
                                                       u16* __restrict__ out,
                                                       int R, int C) {
  __shared__ float tile[64][65];
  const int tilesC = C >> 6;
  const int tilesPerHead = (R >> 6) * tilesC;
  int hb = blockIdx.x;
  int head = hb / tilesPerHead;
  int t = hb - head * tilesPerHead;
  int tr = t / tilesC, tc = t - tr * tilesC;
  const float* ip = in + (size_t)head * R * C + (size_t)tr * 64 * C + (size_t)tc * 64;
  u16* op = out + (size_t)head * R * C + (size_t)tc * 64 * R + (size_t)tr * 64;
  int c = threadIdx.x & 63, r0 = threadIdx.x >> 6;
#pragma unroll
  for (int k = 0; k < 16; ++k) {
    int r = (k << 2) + r0;
    tile[r][c] = ip[(size_t)r * C + c];
  }
  __syncthreads();
#pragma unroll
  for (int k = 0; k < 16; ++k) {
    int orow = (k << 2) + r0;
    op[(size_t)orow * R + c] = f2bf(tile[c][orow]);
  }
}

// ---- fused attention, swapped 32x32 ----
// Layouts (bf16): Qb [h][s][d] (pre-scaled), Kn [h][s][d], Vt [h][d][s].
// Block = 128 q-rows = 4 waves x 32. Per wave, j-tiles of 32.
// mfma_f32_32x32x16_bf16:  A row=lane&31, k=(lane>>5)*8+i (8 contig)
//                          B col=lane&31, k=(lane>>5)*8+i
//                          D col=lane&31, row=(r&3)+8*(r>>2)+4*(lane>>5)
// S^T[j][q] = sum_d K[j][d]*Q[q][d]:  A=K rows, B=Q rows, lane q=lane&31,
//   holds s[r] at j=(r&3)+8*(r>>2)+4*hi  (hi=lane>>5).
// PV: O[q][d] = sum_j P[q][j]V[j][d]: A=P (row=q matches!), B=V^T rows.
__global__ __launch_bounds__(256, 4) void attn_k(const u16* __restrict__ Qb,
                                                 const u16* __restrict__ Kn,
                                                 const u16* __restrict__ Vt,
                                                 float* __restrict__ Og,
                                                 float* __restrict__ Pg) {
  int bid = blockIdx.x;
  // bijective XCD swizzle: 1024 blocks, XCD x gets heads 8x..8x+7 (K+V = 4MB = L2)
  int work = ((bid & 7) << 7) | (bid >> 3);
  int head = work >> 4;
  int rblk = work & 15;
  int lane = threadIdx.x & 63;
  int wv = threadIdx.x >> 6;
  int q = lane & 31;
  int hi = lane >> 5;
  int q0 = (rblk << 7) + (wv << 5);

  // Q B-fragments, resident (d-tiles t=0..3: Qb[q0+q][t*16 + hi*8 .. +7])
  const u16* qp = Qb + (size_t)(head * S_LEN + q0 + q) * DH + hi * 8;
  short8 qf0 = *(const short8*)(qp);
  short8 qf1 = *(const short8*)(qp + 16);
  short8 qf2 = *(const short8*)(qp + 32);
  short8 qf3 = *(const short8*)(qp + 48);

  const u16* kp = Kn + (size_t)head * S_LEN * DH + (size_t)q * DH + hi * 8;
  const u16* vp = Vt + (size_t)head * DH * S_LEN + (size_t)q * S_LEN + hi * 8;

  // ---- pass 1: l[q] = sum_j exp(s) ----
  float ls0 = 0.f, ls1 = 0.f, ls2 = 0.f, ls3 = 0.f;
  for (int j0 = 0; j0 < S_LEN; j0 += 32) {
    const u16* kb = kp + (size_t)j0 * DH;
    short8 k0 = *(const short8*)(kb);
    short8 k1 = *(const short8*)(kb + 16);
    short8 k2 = *(const short8*)(kb + 32);
    short8 k3 = *(const short8*)(kb + 48);
    f32x16 s = {};
    s = __builtin_amdgcn_mfma_f32_32x32x16_bf16(k0, qf0, s, 0, 0, 0);
    s = __builtin_amdgcn_mfma_f32_32x32x16_bf16(k1, qf1, s, 0, 0, 0);
    s = __builtin_amdgcn_mfma_f32_32x32x16_bf16(k2, qf2, s, 0, 0, 0);
    s = __builtin_amdgcn_mfma_f32_32x32x16_bf16(k3, qf3, s, 0, 0, 0);
#pragma unroll
    for (int r = 0; r < 16; r += 4) {
      ls0 += __expf(s[r]);
      ls1 += __expf(s[r + 1]);
      ls2 += __expf(s[r + 2]);
      ls3 += __expf(s[r + 3]);
    }
  }
  float ls = (ls0 + ls1) + (ls2 + ls3);
  ls += __shfl_xor(ls, 32);  // combine hi/lo halves (disjoint j subsets)
  float rl = 1.f / ls;

  // ---- pass 2: P write + O = P*V ----
  f32x16 oa = {}, ob = {};
  float* pb = Pg + (size_t)(head * S_LEN + q0 + q) * S_LEN + hi * 4;

  for (int j0 = 0; j0 < S_LEN; j0 += 32) {
    const u16* kb = kp + (size_t)j0 * DH;
    short8 k0 = *(const short8*)(kb);
    short8 k1 = *(const short8*)(kb + 16);
    short8 k2 = *(const short8*)(kb + 32);
    short8 k3 = *(const short8*)(kb + 48);
    f32x16 s = {};
    s = __builtin_amdgcn_mfma_f32_32x32x16_bf16(k0, qf0, s, 0, 0, 0);
    s = __builtin_amdgcn_mfma_f32_32x32x16_bf16(k1, qf1, s, 0, 0, 0);
    s = __builtin_amdgcn_mfma_f32_32x32x16_bf16(k2, qf2, s, 0, 0, 0);
    s = __builtin_amdgcn_mfma_f32_32x32x16_bf16(k3, qf3, s, 0, 0, 0);

    float p[16];
#pragma unroll
    for (int r = 0; r < 16; ++r) p[r] = __expf(s[r]) * rl;

    // P stores: reg group g holds j = j0 + 8g + 4hi + {0..3} -> one dwordx4.
    // hi/lo lanes + 4 instrs fully dirty each 128B line; nt protects K/V in L2.
#pragma unroll
    for (int g = 0; g < 4; ++g) {
      f32x4 st = {p[4 * g], p[4 * g + 1], p[4 * g + 2], p[4 * g + 3]};
      __builtin_nontemporal_store(st, (f32x4*)(pb + j0 + 8 * g));
    }

    // T12 redistribute: D-layout -> A-frag (k = hi*8+i contiguous j)
    unsigned A0 = pkbf(p[0], p[1]),   A1 = pkbf(p[2], p[3]);
    unsigned B0 = pkbf(p[4], p[5]),   B1 = pkbf(p[6], p[7]);
    plswap(A0, B0);  // A0 -> w0 (lo:{j0,j1} hi:{j8,j9}),  B0 -> w2
    plswap(A1, B1);  // A1 -> w1, B1 -> w3
    unsigned C0 = pkbf(p[8], p[9]),   C1 = pkbf(p[10], p[11]);
    unsigned D0 = pkbf(p[12], p[13]), D1 = pkbf(p[14], p[15]);
    plswap(C0, D0);
    plswap(C1, D1);
    union { unsigned w[4]; short8 v; } pa0u = {{A0, A1, B0, B1}};
    union { unsigned w[4]; short8 v; } pa1u = {{C0, C1, D0, D1}};

    const u16* vj = vp + j0;
    short8 v00 = *(const short8*)(vj);                     // jstep0, d 0..31
    short8 v01 = *(const short8*)(vj + 16);                // jstep1, d 0..31
    short8 v10 = *(const short8*)(vj + 32 * S_LEN);        // jstep0, d 32..63
    short8 v11 = *(const short8*)(vj + 32 * S_LEN + 16);   // jstep1, d 32..63
    oa = __builtin_amdgcn_mfma_f32_32x32x16_bf16(pa0u.v, v00, oa, 0, 0, 0);
    oa = __builtin_amdgcn_mfma_f32_32x32x16_bf16(pa1u.v, v01, oa, 0, 0, 0);
    ob = __builtin_amdgcn_mfma_f32_32x32x16_bf16(pa0u.v, v10, ob, 0, 0, 0);
    ob = __builtin_amdgcn_mfma_f32_32x32x16_bf16(pa1u.v, v11, ob, 0, 0, 0);
  }

  float* og = Og + (size_t)(head * S_LEN + q0) * DH + q;
#pragma unroll
  for (int r = 0; r < 16; ++r) {
    int row = (r & 3) + 8 * (r >> 2) + 4 * hi;
    __builtin_nontemporal_store(oa[r], og + (size_t)row * DH);
    __builtin_nontemporal_store(ob[r], og + (size_t)row * DH + 32);
  }
}

extern "C" void kernel_launch(void* const* d_in, const int* in_sizes, int n_in,
                              void* d_out, int out_size, void* d_ws, size_t ws_size,
                              hipStream_t stream) {
  const float* q = (const float*)d_in[0];
  const float* k = (const float*)d_in[1];  // [b,h,d,s]
  const float* v = (const float*)d_in[2];  // [b,h,s,d]
  float* Og = (float*)d_out;
  float* Pg = Og + (size_t)NHEADS * S_LEN * DH;

  const size_t elems = (size_t)NHEADS * S_LEN * DH;  // 8,388,608
  u16* Qb = (u16*)d_ws;           // bf16 [h][s][d], pre-scaled
  u16* Kn = Qb + elems;           // bf16 [h][s][d]
  u16* Vt = Kn + elems;           // bf16 [h][d][s]

  int n4 = (int)(elems / 4);
  cvt_scale_k<<<n4 / 256, 256, 0, stream>>>(q, Qb, 0.125f, n4);
  transpose_cvt_k<<<NHEADS * (S_LEN / 64), 256, 0, stream>>>(k, Kn, DH, S_LEN);
  transpose_cvt_k<<<NHEADS * (S_LEN / 64), 256, 0, stream>>>(v, Vt, S_LEN, DH);
  attn_k<<<NHEADS * (S_LEN / 128), 256, 0, stream>>>(Qb, Kn, Vt, Og, Pg);
}

// Round 4
// 618.016 us; speedup vs baseline: 1.3734x; 1.3734x over previous
//
#include <hip/hip_runtime.h>

// Scaled-dot-product attention, bs=4, h=16, S=2048, D=64, f32 in/out.
// Outputs O [64,2048,64] and P=attn_weights [64,2048,2048] (f32, 1.07 GB write).
// Swapped-QK^T 32x32 structure: S^T = mfma(K, Q^T) -> j is lane-local per q-row,
// softmax denom needs no cross-lane in loop; P->bf16 A-frags via bf16-pack +
// v_permlane32_swap (no LDS, no barriers). Memory-bound on the P write.
// R3 lesson: NO nontemporal stores -- L2 write-combining is what keeps the
// scattered 16B/lane P stores at the 1.08 GB HBM minimum (R1: minimal; R3 nt: 1.67x).

#define S_LEN 2048
#define DH 64
#define NHEADS 64  // bs*h

typedef short short8 __attribute__((ext_vector_type(8)));   // 8 x bf16
typedef float f32x4 __attribute__((ext_vector_type(4)));
typedef float f32x16 __attribute__((ext_vector_type(16)));
typedef unsigned short u16;

__device__ __forceinline__ u16 f2bf(float f) {
  union { float f; unsigned u; } x;
  x.f = f;
  unsigned r = x.u + 0x7fffu + ((x.u >> 16) & 1u);  // RNE
  return (u16)(r >> 16);
}

__device__ __forceinline__ unsigned pkbf(float a, float b) {
  return (unsigned)f2bf(a) | ((unsigned)f2bf(b) << 16);  // a -> low, b -> high
}

// v_permlane32_swap_b32: new a[32+i]=old b[i]; new b[i]=old a[32+i]
__device__ __forceinline__ void plswap(unsigned& a, unsigned& b) {
  asm("v_permlane32_swap_b32 %0, %1" : "+v"(a), "+v"(b));
}

// ---- pre-pass: Q * scale -> bf16, same layout ----
__global__ __launch_bounds__(256) void cvt_scale_k(const float* __restrict__ in,
                                                   u16* __restrict__ out,
                                                   float scale, int n4) {
  int i = blockIdx.x * 256 + threadIdx.x;
  if (i >= n4) return;
  float4 v = ((const float4*)in)[i];
  union { u16 s[4]; unsigned long long ll; } o;
  o.s[0] = f2bf(v.x * scale); o.s[1] = f2bf(v.y * scale);
  o.s[2] = f2bf(v.z * scale); o.s[3] = f2bf(v.w * scale);
  ((unsigned long long*)out)[i] = o.ll;
}

// ---- pre-pass: per-head transpose [R][C] f32 -> [C][R] bf16 ----
__global__ __launch_bounds__(256) void transpose_cvt_k(const float* __restrict__ in,
                                                       u16* __restrict__ out,
                                                       int R, int C) {
  __shared__ float tile[64][65];
  const int tilesC = C >> 6;
  const int tilesPerHead = (R >> 6) * tilesC;
  int hb = blockIdx.x;
  int head = hb / tilesPerHead;
  int t = hb - head * tilesPerHead;
  int tr = t / tilesC, tc = t - tr * tilesC;
  const float* ip = in + (size_t)head * R * C + (size_t)tr * 64 * C + (size_t)tc * 64;
  u16* op = out + (size_t)head * R * C + (size_t)tc * 64 * R + (size_t)tr * 64;
  int c = threadIdx.x & 63, r0 = threadIdx.x >> 6;
#pragma unroll
  for (int k = 0; k < 16; ++k) {
    int r = (k << 2) + r0;
    tile[r][c] = ip[(size_t)r * C + c];
  }
  __syncthreads();
#pragma unroll
  for (int k = 0; k < 16; ++k) {
    int orow = (k << 2) + r0;
    op[(size_t)orow * R + c] = f2bf(tile[c][orow]);
  }
}

// ---- fused attention, swapped 32x32 ----
// Layouts (bf16): Qb [h][s][d] (pre-scaled), Kn [h][s][d], Vt [h][d][s].
// Block = 128 q-rows = 4 waves x 32. Per wave, j-tiles of 32.
// mfma_f32_32x32x16_bf16:  A row=lane&31, k=(lane>>5)*8+i (8 contig)
//                          B col=lane&31, k=(lane>>5)*8+i
//                          D col=lane&31, row=(r&3)+8*(r>>2)+4*(lane>>5)
// S^T[j][q] = sum_d K[j][d]*Q[q][d]:  A=K rows, B=Q rows, lane q=lane&31,
//   holds s[r] at j=(r&3)+8*(r>>2)+4*hi  (hi=lane>>5).
// PV: O[q][d] = sum_j P[q][j]V[j][d]: A=P (row=q matches!), B=V^T rows.
__global__ __launch_bounds__(256, 4) void attn_k(const u16* __restrict__ Qb,
                                                 const u16* __restrict__ Kn,
                                                 const u16* __restrict__ Vt,
                                                 float* __restrict__ Og,
                                                 float* __restrict__ Pg) {
  int bid = blockIdx.x;
  // bijective XCD swizzle: 1024 blocks, XCD x gets heads 8x..8x+7 (K+V = 4MB = L2)
  int work = ((bid & 7) << 7) | (bid >> 3);
  int head = work >> 4;
  int rblk = work & 15;
  int lane = threadIdx.x & 63;
  int wv = threadIdx.x >> 6;
  int q = lane & 31;
  int hi = lane >> 5;
  int q0 = (rblk << 7) + (wv << 5);

  // Q B-fragments, resident (d-tiles t=0..3: Qb[q0+q][t*16 + hi*8 .. +7])
  const u16* qp = Qb + (size_t)(head * S_LEN + q0 + q) * DH + hi * 8;
  short8 qf0 = *(const short8*)(qp);
  short8 qf1 = *(const short8*)(qp + 16);
  short8 qf2 = *(const short8*)(qp + 32);
  short8 qf3 = *(const short8*)(qp + 48);

  const u16* kp = Kn + (size_t)head * S_LEN * DH + (size_t)q * DH + hi * 8;
  const u16* vp = Vt + (size_t)head * DH * S_LEN + (size_t)q * S_LEN + hi * 8;

  // ---- pass 1: l[q] = sum_j exp(s) ----
  float ls0 = 0.f, ls1 = 0.f, ls2 = 0.f, ls3 = 0.f;
  for (int j0 = 0; j0 < S_LEN; j0 += 32) {
    const u16* kb = kp + (size_t)j0 * DH;
    short8 k0 = *(const short8*)(kb);
    short8 k1 = *(const short8*)(kb + 16);
    short8 k2 = *(const short8*)(kb + 32);
    short8 k3 = *(const short8*)(kb + 48);
    f32x16 s = {};
    s = __builtin_amdgcn_mfma_f32_32x32x16_bf16(k0, qf0, s, 0, 0, 0);
    s = __builtin_amdgcn_mfma_f32_32x32x16_bf16(k1, qf1, s, 0, 0, 0);
    s = __builtin_amdgcn_mfma_f32_32x32x16_bf16(k2, qf2, s, 0, 0, 0);
    s = __builtin_amdgcn_mfma_f32_32x32x16_bf16(k3, qf3, s, 0, 0, 0);
#pragma unroll
    for (int r = 0; r < 16; r += 4) {
      ls0 += __expf(s[r]);
      ls1 += __expf(s[r + 1]);
      ls2 += __expf(s[r + 2]);
      ls3 += __expf(s[r + 3]);
    }
  }
  float ls = (ls0 + ls1) + (ls2 + ls3);
  ls += __shfl_xor(ls, 32);  // combine hi/lo halves (disjoint j subsets)
  float rl = 1.f / ls;

  // ---- pass 2: P write + O = P*V ----
  f32x16 oa = {}, ob = {};
  float* pb = Pg + (size_t)(head * S_LEN + q0 + q) * S_LEN + hi * 4;

  for (int j0 = 0; j0 < S_LEN; j0 += 32) {
    const u16* kb = kp + (size_t)j0 * DH;
    short8 k0 = *(const short8*)(kb);
    short8 k1 = *(const short8*)(kb + 16);
    short8 k2 = *(const short8*)(kb + 32);
    short8 k3 = *(const short8*)(kb + 48);
    f32x16 s = {};
    s = __builtin_amdgcn_mfma_f32_32x32x16_bf16(k0, qf0, s, 0, 0, 0);
    s = __builtin_amdgcn_mfma_f32_32x32x16_bf16(k1, qf1, s, 0, 0, 0);
    s = __builtin_amdgcn_mfma_f32_32x32x16_bf16(k2, qf2, s, 0, 0, 0);
    s = __builtin_amdgcn_mfma_f32_32x32x16_bf16(k3, qf3, s, 0, 0, 0);

    float p[16];
#pragma unroll
    for (int r = 0; r < 16; ++r) p[r] = __expf(s[r]) * rl;

    // P stores: reg group g holds j = j0 + 8g + 4hi + {0..3} -> one dwordx4.
    // Regular stores: L2 merges the 8 partial 16B writes per 128B line (R1-proven).
#pragma unroll
    for (int g = 0; g < 4; ++g) {
      f32x4 st = {p[4 * g], p[4 * g + 1], p[4 * g + 2], p[4 * g + 3]};
      *(f32x4*)(pb + j0 + 8 * g) = st;
    }

    // T12 redistribute: D-layout -> A-frag (k = hi*8+i contiguous j)
    unsigned A0 = pkbf(p[0], p[1]),   A1 = pkbf(p[2], p[3]);
    unsigned B0 = pkbf(p[4], p[5]),   B1 = pkbf(p[6], p[7]);
    plswap(A0, B0);  // A0 -> w0 (lo:{j0,j1} hi:{j8,j9}),  B0 -> w2
    plswap(A1, B1);  // A1 -> w1, B1 -> w3
    unsigned C0 = pkbf(p[8], p[9]),   C1 = pkbf(p[10], p[11]);
    unsigned D0 = pkbf(p[12], p[13]), D1 = pkbf(p[14], p[15]);
    plswap(C0, D0);
    plswap(C1, D1);
    union { unsigned w[4]; short8 v; } pa0u = {{A0, A1, B0, B1}};
    union { unsigned w[4]; short8 v; } pa1u = {{C0, C1, D0, D1}};

    const u16* vj = vp + j0;
    short8 v00 = *(const short8*)(vj);                     // jstep0, d 0..31
    short8 v01 = *(const short8*)(vj + 16);                // jstep1, d 0..31
    short8 v10 = *(const short8*)(vj + 32 * S_LEN);        // jstep0, d 32..63
    short8 v11 = *(const short8*)(vj + 32 * S_LEN + 16);   // jstep1, d 32..63
    oa = __builtin_amdgcn_mfma_f32_32x32x16_bf16(pa0u.v, v00, oa, 0, 0, 0);
    oa = __builtin_amdgcn_mfma_f32_32x32x16_bf16(pa1u.v, v01, oa, 0, 0, 0);
    ob = __builtin_amdgcn_mfma_f32_32x32x16_bf16(pa0u.v, v10, ob, 0, 0, 0);
    ob = __builtin_amdgcn_mfma_f32_32x32x16_bf16(pa1u.v, v11, ob, 0, 0, 0);
  }

  float* og = Og + (size_t)(head * S_LEN + q0) * DH + q;
#pragma unroll
  for (int r = 0; r < 16; ++r) {
    int row = (r & 3) + 8 * (r >> 2) + 4 * hi;
    og[(size_t)row * DH] = oa[r];
    og[(size_t)row * DH + 32] = ob[r];
  }
}

extern "C" void kernel_launch(void* const* d_in, const int* in_sizes, int n_in,
                              void* d_out, int out_size, void* d_ws, size_t ws_size,
                              hipStream_t stream) {
  const float* q = (const float*)d_in[0];
  const float* k = (const float*)d_in[1];  // [b,h,d,s]
  const float* v = (const float*)d_in[2];  // [b,h,s,d]
  float* Og = (float*)d_out;
  float* Pg = Og + (size_t)NHEADS * S_LEN * DH;

  const size_t elems = (size_t)NHEADS * S_LEN * DH;  // 8,388,608
  u16* Qb = (u16*)d_ws;           // bf16 [h][s][d], pre-scaled
  u16* Kn = Qb + elems;           // bf16 [h][s][d]
  u16* Vt = Kn + elems;           // bf16 [h][d][s]

  int n4 = (int)(elems / 4);
  cvt_scale_k<<<n4 / 256, 256, 0, stream>>>(q, Qb, 0.125f, n4);
  transpose_cvt_k<<<NHEADS * (S_LEN / 64), 256, 0, stream>>>(k, Kn, DH, S_LEN);
  transpose_cvt_k<<<NHEADS * (S_LEN / 64), 256, 0, stream>>>(v, Vt, S_LEN, DH);
  attn_k<<<NHEADS * (S_LEN / 128), 256, 0, stream>>>(Qb, Kn, Vt, Og, Pg);
}

// Round 5
// 606.754 us; speedup vs baseline: 1.3989x; 1.0186x over previous
//
#include <hip/hip_runtime.h>

// Scaled-dot-product attention, bs=4, h=16, S=2048, D=64, f32 in/out.
// Outputs O [64,2048,64] and P=attn_weights [64,2048,2048] (f32, 1.07 GB write).
// Swapped-QK^T 32x32 structure: S^T = mfma(K, Q^T) -> j lane-local per q-row.
// R3 lesson: regular stores (L2 write-combining) keep P at the 1.08 GB minimum.
// R4 lesson: VGPR=48 => no prefetch, ~300cyc exposed L2 latency per iter.
// R5: register double-buffer K across iterations + top-of-body V loads.

#define S_LEN 2048
#define DH 64
#define NHEADS 64  // bs*h

typedef short short8 __attribute__((ext_vector_type(8)));   // 8 x bf16
typedef float f32x4 __attribute__((ext_vector_type(4)));
typedef float f32x16 __attribute__((ext_vector_type(16)));
typedef unsigned short u16;

__device__ __forceinline__ u16 f2bf(float f) {
  union { float f; unsigned u; } x;
  x.f = f;
  unsigned r = x.u + 0x7fffu + ((x.u >> 16) & 1u);  // RNE
  return (u16)(r >> 16);
}

__device__ __forceinline__ unsigned pkbf(float a, float b) {
  return (unsigned)f2bf(a) | ((unsigned)f2bf(b) << 16);  // a -> low, b -> high
}

// v_permlane32_swap_b32: new a[32+i]=old b[i]; new b[i]=old a[32+i]
__device__ __forceinline__ void plswap(unsigned& a, unsigned& b) {
  asm("v_permlane32_swap_b32 %0, %1" : "+v"(a), "+v"(b));
}

// ---- pre-pass: Q * scale -> bf16, same layout ----
__global__ __launch_bounds__(256) void cvt_scale_k(const float* __restrict__ in,
                                                   u16* __restrict__ out,
                                                   float scale, int n4) {
  int i = blockIdx.x * 256 + threadIdx.x;
  if (i >= n4) return;
  float4 v = ((const float4*)in)[i];
  union { u16 s[4]; unsigned long long ll; } o;
  o.s[0] = f2bf(v.x * scale); o.s[1] = f2bf(v.y * scale);
  o.s[2] = f2bf(v.z * scale); o.s[3] = f2bf(v.w * scale);
  ((unsigned long long*)out)[i] = o.ll;
}

// ---- pre-pass: per-head transpose [R][C] f32 -> [C][R] bf16 ----
__global__ __launch_bounds__(256) void transpose_cvt_k(const float* __restrict__ in,
                                                       u16* __restrict__ out,
                                                       int R, int C) {
  __shared__ float tile[64][65];
  const int tilesC = C >> 6;
  const int tilesPerHead = (R >> 6) * tilesC;
  int hb = blockIdx.x;
  int head = hb / tilesPerHead;
  int t = hb - head * tilesPerHead;
  int tr = t / tilesC, tc = t - tr * tilesC;
  const float* ip = in + (size_t)head * R * C + (size_t)tr * 64 * C + (size_t)tc * 64;
  u16* op = out + (size_t)head * R * C + (size_t)tc * 64 * R + (size_t)tr * 64;
  int c = threadIdx.x & 63, r0 = threadIdx.x >> 6;
#pragma unroll
  for (int k = 0; k < 16; ++k) {
    int r = (k << 2) + r0;
    tile[r][c] = ip[(size_t)r * C + c];
  }
  __syncthreads();
#pragma unroll
  for (int k = 0; k < 16; ++k) {
    int orow = (k << 2) + r0;
    op[(size_t)orow * R + c] = f2bf(tile[c][orow]);
  }
}

// ---- fused attention, swapped 32x32, K reg-double-buffered ----
// Layouts (bf16): Qb [h][s][d] (pre-scaled), Kn [h][s][d], Vt [h][d][s].
// Block = 128 q-rows = 4 waves x 32. Per wave, j-tiles of 32.
// mfma_f32_32x32x16_bf16:  A row=lane&31, k=(lane>>5)*8+i (8 contig)
//                          B col=lane&31, k=(lane>>5)*8+i
//                          D col=lane&31, row=(r&3)+8*(r>>2)+4*(lane>>5)
__global__ __launch_bounds__(256, 3) void attn_k(const u16* __restrict__ Qb,
                                                 const u16* __restrict__ Kn,
                                                 const u16* __restrict__ Vt,
                                                 float* __restrict__ Og,
                                                 float* __restrict__ Pg) {
  int bid = blockIdx.x;
  // bijective XCD swizzle: 1024 blocks, XCD x gets heads 8x..8x+7 (K+V = 4MB = L2)
  int work = ((bid & 7) << 7) | (bid >> 3);
  int head = work >> 4;
  int rblk = work & 15;
  int lane = threadIdx.x & 63;
  int wv = threadIdx.x >> 6;
  int q = lane & 31;
  int hi = lane >> 5;
  int q0 = (rblk << 7) + (wv << 5);

  // Q B-fragments, resident
  const u16* qp = Qb + (size_t)(head * S_LEN + q0 + q) * DH + hi * 8;
  short8 qf0 = *(const short8*)(qp);
  short8 qf1 = *(const short8*)(qp + 16);
  short8 qf2 = *(const short8*)(qp + 32);
  short8 qf3 = *(const short8*)(qp + 48);

  const u16* kp = Kn + (size_t)head * S_LEN * DH + (size_t)q * DH + hi * 8;
  const u16* vp = Vt + (size_t)head * DH * S_LEN + (size_t)q * S_LEN + hi * 8;

  // ---- pass 1: l[q] = sum_j exp(s); K double-buffered ----
  float ls0 = 0.f, ls1 = 0.f, ls2 = 0.f, ls3 = 0.f;
  short8 kc0 = *(const short8*)(kp);
  short8 kc1 = *(const short8*)(kp + 16);
  short8 kc2 = *(const short8*)(kp + 32);
  short8 kc3 = *(const short8*)(kp + 48);
  for (int j0 = 0; j0 < S_LEN; j0 += 32) {
    int jn = (j0 + 32) & (S_LEN - 1);          // wrap: last prefetch is harmless
    const u16* kb = kp + (size_t)jn * DH;
    short8 kn0 = *(const short8*)(kb);
    short8 kn1 = *(const short8*)(kb + 16);
    short8 kn2 = *(const short8*)(kb + 32);
    short8 kn3 = *(const short8*)(kb + 48);
    f32x16 s = {};
    s = __builtin_amdgcn_mfma_f32_32x32x16_bf16(kc0, qf0, s, 0, 0, 0);
    s = __builtin_amdgcn_mfma_f32_32x32x16_bf16(kc1, qf1, s, 0, 0, 0);
    s = __builtin_amdgcn_mfma_f32_32x32x16_bf16(kc2, qf2, s, 0, 0, 0);
    s = __builtin_amdgcn_mfma_f32_32x32x16_bf16(kc3, qf3, s, 0, 0, 0);
#pragma unroll
    for (int r = 0; r < 16; r += 4) {
      ls0 += __expf(s[r]);
      ls1 += __expf(s[r + 1]);
      ls2 += __expf(s[r + 2]);
      ls3 += __expf(s[r + 3]);
    }
    kc0 = kn0; kc1 = kn1; kc2 = kn2; kc3 = kn3;
  }
  float ls = (ls0 + ls1) + (ls2 + ls3);
  ls += __shfl_xor(ls, 32);  // combine hi/lo halves (disjoint j subsets)
  float rl = 1.f / ls;

  // ---- pass 2: P write + O = P*V; K dbuf + early V loads ----
  f32x16 oa = {}, ob = {};
  float* pb = Pg + (size_t)(head * S_LEN + q0 + q) * S_LEN + hi * 4;

  // kc* already holds j0=0 tile (wrapped prefetch from pass 1)
  for (int j0 = 0; j0 < S_LEN; j0 += 32) {
    int jn = (j0 + 32) & (S_LEN - 1);
    const u16* kb = kp + (size_t)jn * DH;
    short8 kn0 = *(const short8*)(kb);
    short8 kn1 = *(const short8*)(kb + 16);
    short8 kn2 = *(const short8*)(kb + 32);
    short8 kn3 = *(const short8*)(kb + 48);
    // V for CURRENT tile issued early: latency hides under QK^T+exp+stores
    const u16* vj = vp + j0;
    short8 v00 = *(const short8*)(vj);                     // jstep0, d 0..31
    short8 v01 = *(const short8*)(vj + 16);                // jstep1, d 0..31
    short8 v10 = *(const short8*)(vj + 32 * S_LEN);        // jstep0, d 32..63
    short8 v11 = *(const short8*)(vj + 32 * S_LEN + 16);   // jstep1, d 32..63

    f32x16 s = {};
    s = __builtin_amdgcn_mfma_f32_32x32x16_bf16(kc0, qf0, s, 0, 0, 0);
    s = __builtin_amdgcn_mfma_f32_32x32x16_bf16(kc1, qf1, s, 0, 0, 0);
    s = __builtin_amdgcn_mfma_f32_32x32x16_bf16(kc2, qf2, s, 0, 0, 0);
    s = __builtin_amdgcn_mfma_f32_32x32x16_bf16(kc3, qf3, s, 0, 0, 0);

    float p[16];
#pragma unroll
    for (int r = 0; r < 16; ++r) p[r] = __expf(s[r]) * rl;

    // P stores: reg group g holds j = j0 + 8g + 4hi + {0..3} -> one dwordx4.
    // Regular stores: L2 merges the 8 partial 16B writes per 128B line.
#pragma unroll
    for (int g = 0; g < 4; ++g) {
      f32x4 st = {p[4 * g], p[4 * g + 1], p[4 * g + 2], p[4 * g + 3]};
      *(f32x4*)(pb + j0 + 8 * g) = st;
    }

    // T12 redistribute: D-layout -> A-frag (k = hi*8+i contiguous j)
    unsigned A0 = pkbf(p[0], p[1]),   A1 = pkbf(p[2], p[3]);
    unsigned B0 = pkbf(p[4], p[5]),   B1 = pkbf(p[6], p[7]);
    plswap(A0, B0);
    plswap(A1, B1);
    unsigned C0 = pkbf(p[8], p[9]),   C1 = pkbf(p[10], p[11]);
    unsigned D0 = pkbf(p[12], p[13]), D1 = pkbf(p[14], p[15]);
    plswap(C0, D0);
    plswap(C1, D1);
    union { unsigned w[4]; short8 v; } pa0u = {{A0, A1, B0, B1}};
    union { unsigned w[4]; short8 v; } pa1u = {{C0, C1, D0, D1}};

    oa = __builtin_amdgcn_mfma_f32_32x32x16_bf16(pa0u.v, v00, oa, 0, 0, 0);
    oa = __builtin_amdgcn_mfma_f32_32x32x16_bf16(pa1u.v, v01, oa, 0, 0, 0);
    ob = __builtin_amdgcn_mfma_f32_32x32x16_bf16(pa0u.v, v10, ob, 0, 0, 0);
    ob = __builtin_amdgcn_mfma_f32_32x32x16_bf16(pa1u.v, v11, ob, 0, 0, 0);

    kc0 = kn0; kc1 = kn1; kc2 = kn2; kc3 = kn3;
  }

  float* og = Og + (size_t)(head * S_LEN + q0) * DH + q;
#pragma unroll
  for (int r = 0; r < 16; ++r) {
    int row = (r & 3) + 8 * (r >> 2) + 4 * hi;
    og[(size_t)row * DH] = oa[r];
    og[(size_t)row * DH + 32] = ob[r];
  }
}

extern "C" void kernel_launch(void* const* d_in, const int* in_sizes, int n_in,
                              void* d_out, int out_size, void* d_ws, size_t ws_size,
                              hipStream_t stream) {
  const float* q = (const float*)d_in[0];
  const float* k = (const float*)d_in[1];  // [b,h,d,s]
  const float* v = (const float*)d_in[2];  // [b,h,s,d]
  float* Og = (float*)d_out;
  float* Pg = Og + (size_t)NHEADS * S_LEN * DH;

  const size_t elems = (size_t)NHEADS * S_LEN * DH;  // 8,388,608
  u16* Qb = (u16*)d_ws;           // bf16 [h][s][d], pre-scaled
  u16* Kn = Qb + elems;           // bf16 [h][s][d]
  u16* Vt = Kn + elems;           // bf16 [h][d][s]

  int n4 = (int)(elems / 4);
  cvt_scale_k<<<n4 / 256, 256, 0, stream>>>(q, Qb, 0.125f, n4);
  transpose_cvt_k<<<NHEADS * (S_LEN / 64), 256, 0, stream>>>(k, Kn, DH, S_LEN);
  transpose_cvt_k<<<NHEADS * (S_LEN / 64), 256, 0, stream>>>(v, Vt, S_LEN, DH);
  attn_k<<<NHEADS * (S_LEN / 128), 256, 0, stream>>>(Qb, Kn, Vt, Og, Pg);
}